// Round 8
// baseline (760.000 us; speedup 1.0000x reference)
//
#include <hip/hip_runtime.h>
#include <cstddef>

#define CCH 768
#define CHUNK 262144u

// ---- d_out scratch carve (byte offsets), chunk = 256 KiB ----
// [0,48)    Yt (bf16)        -> tail memcpy
// [48,96)   Hh (bf16)        -> restored in untr
// [96,114)  W2T              -> restored in untr
// [114,115) aux              -> restored in untr
// [115,121) partial          -> restored in untr
// [121,169) Xh               -> restored in exp2
// [169,174) GWh              -> restored in exp1
// [174,192) W1T              -> restored in exp2
// early s4 [192,768) + s8 + s16 -> gate 620, exp1 280, exp2 252
#define OFF_YT    0u
#define OFF_HH    12582912u
#define OFF_W2T   25165824u
#define OFF_AUX   29884416u
#define OFF_PART  30146560u
#define OFF_XH    31719424u
#define OFF_GWH   44302336u
#define OFF_W1T   45613056u
#define TAILBYTES 12582912u
#define DELTA     0.01f

typedef __attribute__((ext_vector_type(8))) short short8v;
typedef __attribute__((ext_vector_type(4))) float f32x4;

__device__ __forceinline__ void gl16(const void* g, void* l) {
    __builtin_amdgcn_global_load_lds(
        (const __attribute__((address_space(1))) void*)g,
        (__attribute__((address_space(3))) void*)l, 16, 0, 0);
}

__device__ __forceinline__ void copy_chunk(int g, const char* s4b, const char* s8b,
                                           const char* s16b, char* bb) {
    const char* src = (g < 768) ? s4b + (size_t)g * CHUNK
                    : (g < 1152) ? s8b + (size_t)(g - 768) * CHUNK
                                 : s16b + (size_t)(g - 1152) * CHUNK;
    const uint4* s = (const uint4*)src;
    uint4* d = (uint4*)(bb + (size_t)g * CHUNK);
    int t = threadIdx.x;
#pragma unroll 8
    for (int it = 0; it < 64; ++it) d[it * 256 + t] = s[it * 256 + t];
}

__device__ __forceinline__ float gelu_tanh(float x) {
    // JAX default gelu (approximate=True)
    float u = 0.7978845608028654f * (x + 0.044715f * x * x * x);
    float e = __expf(2.0f * u);
    float t = 1.0f - 2.0f / (e + 1.0f);
    return 0.5f * x * (1.0f + t);
}

__device__ __forceinline__ short f2b(float f) {
    unsigned u = __float_as_uint(f);
    unsigned r = (u + 0x7FFFu + ((u >> 16) & 1u)) >> 16;
    return (short)r;
}

__device__ __forceinline__ float b2f(short s) {
    return __uint_as_float(((unsigned)(unsigned short)s) << 16);
}

// z<8: BCHW->token-major bf16 transpose of s32 (batch z). z==8: gate W1 bf16
// transposed convert. Also zeroes counts/cursors/fixcnt.
__global__ __launch_bounds__(256) void k_prep(const float* __restrict__ s32,
                                              const float* __restrict__ gw1,
                                              short* __restrict__ Xh,
                                              short* __restrict__ GWh,
                                              int* __restrict__ az) {
    int z = blockIdx.z;
    int tx = threadIdx.x, ty = threadIdx.y;
    if (z == 0 && blockIdx.x == 0 && blockIdx.y == 0 && ty == 0 && tx < 16)
        az[tx] = 0;
    __shared__ float tile[32][33];
    if (z < 8) {
        int c0 = blockIdx.y * 32, hw0 = blockIdx.x * 32;
        const float* s = s32 + (size_t)z * CCH * 1024;
#pragma unroll
        for (int i = 0; i < 4; ++i)
            tile[ty + 8 * i][tx] = s[(size_t)(c0 + ty + 8 * i) * 1024 + hw0 + tx];
        __syncthreads();
#pragma unroll
        for (int i = 0; i < 4; ++i) {
            int r = ty + 8 * i;
            int n = z * 1024 + hw0 + r;
            Xh[(size_t)n * CCH + c0 + tx] = f2b(tile[tx][r]);
        }
    } else {
        if (blockIdx.x >= 24) return;
        int ci0 = blockIdx.x * 32, co0 = blockIdx.y * 32;
#pragma unroll
        for (int i = 0; i < 4; ++i)
            tile[ty + 8 * i][tx] = gw1[(size_t)(ci0 + ty + 8 * i) * CCH + co0 + tx];
        __syncthreads();
#pragma unroll
        for (int i = 0; i < 4; ++i) {
            int co = co0 + ty + 8 * i;
            GWh[(size_t)co * CCH + ci0 + tx] = f2b(tile[tx][ty + 8 * i]);
        }
    }
}

// 128x128-tile bf16 MFMA GEMM, 4 waves (64x64 quadrants), BK=64, 2-phase
// double-buffered global_load_lds pipeline. Appended copy chunks per mode;
// MODE 0 additionally carries 4608 expert-weight transpose/convert blocks.
// MODE 0: partial logits = gelu(Xh@GWh^T + gb1) @ W2-slice -> partial[12][8192][4]
// MODE 1: Hh[ofs+p] = f2b(gelu(Xh[perm] @ W1T^T + eb1))
// MODE 2: Yt[perm[ofs+p]] = f2b((Hh @ W2T^T + eb2)*gval)   (bf16, token-major)
template <int MODE>
__global__ __launch_bounds__(256) void k_mfma(const short* __restrict__ Ahp,
                                              const short* __restrict__ Bhp,
                                              const float* __restrict__ bias,
                                              const float* __restrict__ gw2,
                                              const int* __restrict__ perm,
                                              const int* __restrict__ counts,
                                              const float* __restrict__ gval,
                                              short* __restrict__ Yt,
                                              short* __restrict__ Hout,
                                              float* __restrict__ partial,
                                              const float* __restrict__ ew1,
                                              const float* __restrict__ ew2,
                                              short* __restrict__ W1T,
                                              short* __restrict__ W2T,
                                              const char* __restrict__ s4b,
                                              const char* __restrict__ s8b,
                                              const char* __restrict__ s16b,
                                              char* __restrict__ bb,
                                              int ngemm, int ncopy) {
    __shared__ __align__(16) short lds[32768];
    int bid = blockIdx.x;
    int t = threadIdx.x;
    if (bid >= ngemm) {
        int i = bid - ngemm;
        if (i < ncopy) {
            int g;
            if (MODE == 0) g = 192 + i;
            else if (MODE == 1) g = (i < 5) ? 169 + i : 812 + (i - 5);
            else g = (i < 48) ? 121 + i : (i < 66) ? 174 + (i - 48) : 1092 + (i - 66);
            copy_chunk(g, s4b, s8b, s16b, bb);
        } else if (MODE == 0) {
            int j = i - ncopy;  // 0..4607 expert-weight converts
            int mat = j / 576, q = j % 576;
            int ci0 = (q % 24) * 32, co0 = (q / 24) * 32;
            const float* src = (mat < 4 ? ew1 : ew2) + (size_t)(mat & 3) * CCH * CCH;
            short* dst = (mat < 4 ? W1T : W2T) + (size_t)(mat & 3) * CCH * CCH;
            float* tile = (float*)lds;  // [32][33]
            int tx = t & 31, ty = t >> 5;
#pragma unroll
            for (int i4 = 0; i4 < 4; ++i4)
                tile[(ty + 8 * i4) * 33 + tx] =
                    src[(size_t)(ci0 + ty + 8 * i4) * CCH + co0 + tx];
            __syncthreads();
#pragma unroll
            for (int i4 = 0; i4 < 4; ++i4) {
                int co = co0 + ty + 8 * i4;
                dst[(size_t)co * CCH + ci0 + tx] = f2b(tile[tx * 33 + ty + 8 * i4]);
            }
        }
        return;
    }

    int cbk = bid % 6;
    int mt = bid / 6;
    int c0 = cbk * 128;
    int e = 0, ts = mt, cnt = 1 << 30, ofs = 0, mrow0 = 0;
    if (MODE == 0) {
        mrow0 = mt * 128;
    } else {
        e = mt >> 6;
        ts = mt & 63;
        int n0 = counts[0], n1 = counts[1], n2 = counts[2], n3 = counts[3];
        cnt = (e == 0) ? n0 : (e == 1) ? n1 : (e == 2) ? n2 : n3;
        if (ts * 128 >= cnt) return;
        ofs = (e > 0 ? n0 : 0) + (e > 1 ? n1 : 0) + (e > 2 ? n2 : 0);
    }

    int lane = t & 63, w = t >> 6;
    int wr = w >> 1, wc = w & 1;
    int lrow = lane & 15, lk8 = lane >> 4;

    const short* aS[4];
    const short* bS[4];
    int dA[4];
    size_t eoff = MODE ? (size_t)e * CCH * CCH : 0;
#pragma unroll
    for (int i = 0; i < 4; ++i) {
        int c = 4 * w + i;
        int g = c >> 1, ph = c & 1;
        int row = g * 16 + lrow;
        int koff = ph * 32 + lk8 * 8;
        int arow;
        if (MODE == 0) {
            arow = mrow0 + row;
        } else {
            int pl = ts * 128 + row;
            int pc = pl < cnt ? pl : cnt - 1;
            arow = (MODE == 1) ? perm[ofs + pc] : (ofs + pc);
        }
        aS[i] = Ahp + (size_t)arow * CCH + koff;
        bS[i] = Bhp + eoff + (size_t)(c0 + row) * CCH + koff;
        dA[i] = c * 512;
    }

    f32x4 acc[4][4] = {};
    auto stage = [&](int b, int k0) {
        short* L = lds + b * 16384;
#pragma unroll
        for (int i = 0; i < 4; ++i) {
            gl16(aS[i] + k0, L + dA[i]);
            gl16(bS[i] + k0, L + 8192 + dA[i]);
        }
    };
    stage(0, 0);
    __syncthreads();
    for (int tt = 0; tt < 12; ++tt) {
        int cur = tt & 1;
        if (tt < 11) stage(cur ^ 1, (tt + 1) * 64);
        const short* L = lds + cur * 16384;
#pragma unroll
        for (int kk = 0; kk < 2; ++kk) {
            short8v af[4], bf[4];
#pragma unroll
            for (int m = 0; m < 4; ++m)
                af[m] = *(const short8v*)(L + (((wr * 4 + m) * 2 + kk) * 64 + lane) * 8);
#pragma unroll
            for (int n = 0; n < 4; ++n)
                bf[n] = *(const short8v*)(L + 8192 + (((wc * 4 + n) * 2 + kk) * 64 + lane) * 8);
#pragma unroll
            for (int m = 0; m < 4; ++m)
#pragma unroll
                for (int n = 0; n < 4; ++n)
                    acc[m][n] = __builtin_amdgcn_mfma_f32_16x16x32_bf16(af[m], bf[n], acc[m][n], 0, 0, 0);
        }
        __syncthreads();
    }

    int cl = lane & 15, rh = (lane >> 4) * 4;
    if (MODE == 0) {
        int cb2 = cbk * 2 + wc;
        float bv[4];
        float4 w2v[4];
#pragma unroll
        for (int n_ = 0; n_ < 4; ++n_) {
            int col = c0 + wc * 64 + n_ * 16 + cl;
            bv[n_] = bias[col];
            w2v[n_] = *(const float4*)(gw2 + col * 4);
        }
#pragma unroll
        for (int m = 0; m < 4; ++m) {
#pragma unroll
            for (int ri = 0; ri < 4; ++ri) {
                float s0 = 0.f, s1 = 0.f, s2 = 0.f, s3 = 0.f;
#pragma unroll
                for (int n_ = 0; n_ < 4; ++n_) {
                    float g = gelu_tanh(acc[m][n_][ri] + bv[n_]);
                    s0 = fmaf(g, w2v[n_].x, s0);
                    s1 = fmaf(g, w2v[n_].y, s1);
                    s2 = fmaf(g, w2v[n_].z, s2);
                    s3 = fmaf(g, w2v[n_].w, s3);
                }
#pragma unroll
                for (int off = 1; off < 16; off <<= 1) {
                    s0 += __shfl_xor(s0, off);
                    s1 += __shfl_xor(s1, off);
                    s2 += __shfl_xor(s2, off);
                    s3 += __shfl_xor(s3, off);
                }
                if (cl == 0) {
                    int row = mrow0 + wr * 64 + m * 16 + rh + ri;
                    float4 pv;
                    pv.x = s0; pv.y = s1; pv.z = s2; pv.w = s3;
                    *(float4*)(partial + (size_t)(cb2 * 8192 + row) * 4) = pv;
                }
            }
        }
    } else {
#pragma unroll
        for (int n = 0; n < 4; ++n) {
            int col = c0 + wc * 64 + n * 16 + cl;
            float bv = bias[e * CCH + col];
#pragma unroll
            for (int m = 0; m < 4; ++m) {
#pragma unroll
                for (int ri = 0; ri < 4; ++ri) {
                    int p = ts * 128 + wr * 64 + m * 16 + rh + ri;
                    if (p < cnt) {
                        float v = acc[m][n][ri] + bv;
                        if (MODE == 1) {
                            Hout[(size_t)(ofs + p) * CCH + col] = f2b(gelu_tanh(v));
                        } else {
                            int nn = perm[ofs + p];
                            Yt[(size_t)nn * CCH + col] = f2b(v * gval[nn]);
                        }
                    }
                }
            }
        }
    }
}

// sum 12 partial slabs + b2; finalize clear-margin tokens, defer near-ties
__global__ __launch_bounds__(256) void k_route(const float* __restrict__ partial,
                                               const float* __restrict__ b2,
                                               int* __restrict__ idx,
                                               float* __restrict__ gval,
                                               int* __restrict__ counts,
                                               int* __restrict__ fixcnt,
                                               int* __restrict__ fixlist) {
    int n = blockIdx.x * 256 + threadIdx.x;
    float l0 = b2[0], l1 = b2[1], l2 = b2[2], l3 = b2[3];
#pragma unroll
    for (int p = 0; p < 12; ++p) {
        float4 v = *(const float4*)(partial + ((size_t)p * 8192 + n) * 4);
        l0 += v.x; l1 += v.y; l2 += v.z; l3 += v.w;
    }
    int e = 0;
    float m1 = l0;
    if (l1 > m1) { m1 = l1; e = 1; }
    if (l2 > m1) { m1 = l2; e = 2; }
    if (l3 > m1) { m1 = l3; e = 3; }
    float m2 = -3.4e38f;
    if (e != 0 && l0 > m2) m2 = l0;
    if (e != 1 && l1 > m2) m2 = l1;
    if (e != 2 && l2 > m2) m2 = l2;
    if (e != 3 && l3 > m2) m2 = l3;
    if (m1 - m2 >= DELTA) {
        float s = __expf(l0 - m1) + __expf(l1 - m1) + __expf(l2 - m1) + __expf(l3 - m1);
        idx[n] = e;
        gval[n] = 1.0f / s;
        atomicAdd(counts + e, 1);
    } else {
        int pos = atomicAdd(fixcnt, 1);
        fixlist[pos] = n;
    }
}

// exact f32 gate recompute for near-tie tokens (4 tokens/block)
__global__ __launch_bounds__(256) void k_fix(const float* __restrict__ s32,
                                             const float* __restrict__ gw1,
                                             const float* __restrict__ gb1,
                                             const float* __restrict__ gw2,
                                             const float* __restrict__ gb2,
                                             const int* __restrict__ fixcnt,
                                             const int* __restrict__ fixlist,
                                             int* __restrict__ idx,
                                             float* __restrict__ gval,
                                             int* __restrict__ counts) {
    __shared__ float xb[4][768];
    __shared__ float red[4][4][4];  // [tok][wave][e]
    int t = threadIdx.x;
    int lane = t & 63, w = t >> 6;
    int nfix = *fixcnt;
    for (int g0 = blockIdx.x * 4; g0 < nfix; g0 += 256 * 4) {
        int nt = nfix - g0 < 4 ? nfix - g0 : 4;
        for (int tt = 0; tt < nt; ++tt) {
            int n = fixlist[g0 + tt];
            int b = n >> 10, hw = n & 1023;
            for (int c = t; c < 768; c += 256)
                xb[tt][c] = s32[(((size_t)(b * CCH + c)) << 10) | (size_t)hw];
        }
        __syncthreads();
        float l[4][4] = {};
#pragma unroll
        for (int jj = 0; jj < 3; ++jj) {
            int j = t + jj * 256;
            float b1 = gb1[j];
            float h0 = b1, h1 = b1, h2 = b1, h3 = b1;
#pragma unroll 4
            for (int c = 0; c < 768; ++c) {
                float wv = gw1[(size_t)c * CCH + j];
                h0 = fmaf(xb[0][c], wv, h0);
                h1 = fmaf(xb[1][c], wv, h1);
                h2 = fmaf(xb[2][c], wv, h2);
                h3 = fmaf(xb[3][c], wv, h3);
            }
            float4 w2 = *(const float4*)(gw2 + j * 4);
            float hh[4] = {gelu_tanh(h0), gelu_tanh(h1), gelu_tanh(h2), gelu_tanh(h3)};
#pragma unroll
            for (int tt = 0; tt < 4; ++tt) {
                l[tt][0] = fmaf(hh[tt], w2.x, l[tt][0]);
                l[tt][1] = fmaf(hh[tt], w2.y, l[tt][1]);
                l[tt][2] = fmaf(hh[tt], w2.z, l[tt][2]);
                l[tt][3] = fmaf(hh[tt], w2.w, l[tt][3]);
            }
        }
#pragma unroll
        for (int tt = 0; tt < 4; ++tt)
#pragma unroll
            for (int e = 0; e < 4; ++e) {
                float v = l[tt][e];
#pragma unroll
                for (int off = 32; off; off >>= 1) v += __shfl_xor(v, off);
                if (lane == 0) red[tt][w][e] = v;
            }
        __syncthreads();
        if (t < nt) {
            int tt = t;
            float le[4];
#pragma unroll
            for (int e = 0; e < 4; ++e)
                le[e] = gb2[e] + red[tt][0][e] + red[tt][1][e] + red[tt][2][e] + red[tt][3][e];
            int e1 = 0;
            float m = le[0];
            if (le[1] > m) { m = le[1]; e1 = 1; }
            if (le[2] > m) { m = le[2]; e1 = 2; }
            if (le[3] > m) { m = le[3]; e1 = 3; }
            float s = __expf(le[0] - m) + __expf(le[1] - m) + __expf(le[2] - m) + __expf(le[3] - m);
            int n = fixlist[g0 + tt];
            idx[n] = e1;
            gval[n] = 1.0f / s;
            atomicAdd(counts + e1, 1);
        }
        __syncthreads();
    }
}

// scatter with in-register prefix over the finalized counts
__global__ __launch_bounds__(256) void k_scatter(const int* __restrict__ idx,
                                                 const int* __restrict__ counts,
                                                 int* __restrict__ cursors,
                                                 int* __restrict__ perm) {
    int n = blockIdx.x * 256 + threadIdx.x;
    int e = idx[n];
    int run = 0;
#pragma unroll
    for (int ee = 0; ee < 4; ++ee) {
        int c = counts[ee];
        if (e == ee) {
            int pos = run + atomicAdd(cursors + ee, 1);
            perm[pos] = n;
        }
        run += c;
    }
}

// out32 = Yt(bf16 token-major) + s32 (coalesced); plus restore-copy chunks
__global__ __launch_bounds__(256) void k_untr(const short* __restrict__ Yt,
                                              const float* __restrict__ s32,
                                              float* __restrict__ out32,
                                              const char* __restrict__ s4b,
                                              const char* __restrict__ s8b,
                                              const char* __restrict__ s16b,
                                              char* __restrict__ bb,
                                              int ncopy) {
    int bid = blockIdx.x;
    if (bid >= 6144) {
        int i = bid - 6144;
        if (i < ncopy) copy_chunk(48 + i, s4b, s8b, s16b, bb);
        return;
    }
    __shared__ float tile[32][33];
    int hw0 = (bid & 31) * 32;
    int c0 = ((bid >> 5) % 24) * 32;
    int b = bid / 768;
    int t = threadIdx.x;
    int tx = t & 31, ty = t >> 5;
#pragma unroll
    for (int i = 0; i < 4; ++i) {
        int hwl = ty + 8 * i;
        tile[hwl][tx] = b2f(Yt[(size_t)(b * 1024 + hw0 + hwl) * CCH + c0 + tx]);
    }
    __syncthreads();
    const float* sp = s32 + (size_t)b * CCH * 1024;
    float* op = out32 + (size_t)b * CCH * 1024;
#pragma unroll
    for (int i = 0; i < 4; ++i) {
        size_t a = (size_t)(c0 + ty + 8 * i) * 1024 + hw0 + tx;
        op[a] = tile[tx][ty + 8 * i] + sp[a];
    }
}

extern "C" void kernel_launch(void* const* d_in, const int* in_sizes, int n_in,
                              void* d_out, int out_size, void* d_ws, size_t ws_size,
                              hipStream_t stream) {
    const float* s4  = (const float*)d_in[0];
    const float* s8  = (const float*)d_in[1];
    const float* s16 = (const float*)d_in[2];
    const float* s32 = (const float*)d_in[3];
    const float* gw1 = (const float*)d_in[4];
    const float* gb1 = (const float*)d_in[5];
    const float* gw2 = (const float*)d_in[6];
    const float* gb2 = (const float*)d_in[7];
    const float* ew1 = (const float*)d_in[8];
    const float* eb1 = (const float*)d_in[9];
    const float* ew2 = (const float*)d_in[10];
    const float* eb2 = (const float*)d_in[11];

    char* bb = (char*)d_out;
    short* Yt      = (short*)(bb + OFF_YT);
    short* Hh      = (short*)(bb + OFF_HH);
    short* W2T     = (short*)(bb + OFF_W2T);
    int*   iaux    = (int*)(bb + OFF_AUX);
    int*   idx     = iaux;            // 8192
    int*   perm    = iaux + 8192;     // 8192
    int*   counts  = iaux + 16384;    // 4
    int*   cursors = iaux + 16388;    // 4
    int*   fixcnt  = iaux + 16392;    // 1 (+pad)
    float* gval    = (float*)(iaux + 16400);  // 8192
    int*   fixlist = iaux + 24592;    // 8192
    float* partial = (float*)(bb + OFF_PART);
    short* Xh      = (short*)(bb + OFF_XH);
    short* GWh     = (short*)(bb + OFF_GWH);
    short* W1T     = (short*)(bb + OFF_W1T);
    float* out32   = (float*)(bb + (size_t)1344 * CHUNK);

    k_prep<<<dim3(32, 24, 9), dim3(32, 8), 0, stream>>>(s32, gw1, Xh, GWh, iaux + 16384);
    // gate (hi-bf16 GEMM + fused W2 partials) + 620 copies + 4608 ew converts
    k_mfma<0><<<384 + 620 + 4608, 256, 0, stream>>>(Xh, GWh, gb1, gw2, perm, counts,
                                                    gval, Yt, Hh, partial, ew1, ew2,
                                                    W1T, W2T, (const char*)s4,
                                                    (const char*)s8, (const char*)s16,
                                                    bb, 384, 620);
    k_route<<<32, 256, 0, stream>>>(partial, gb2, idx, gval, counts, fixcnt, fixlist);
    k_fix<<<256, 256, 0, stream>>>(s32, gw1, gb1, gw2, gb2, fixcnt, fixlist,
                                   idx, gval, counts);
    k_scatter<<<32, 256, 0, stream>>>(idx, counts, cursors, perm);
    // expert layer 1 + GWh restore + 280 early copies
    k_mfma<1><<<1536 + 285, 256, 0, stream>>>(Xh, W1T, eb1, gw2, perm, counts,
                                              gval, Yt, Hh, partial, ew1, ew2,
                                              W1T, W2T, (const char*)s4,
                                              (const char*)s8, (const char*)s16,
                                              bb, 1536, 285);
    // expert layer 2 + Xh/W1T restores + 252 early copies
    k_mfma<2><<<1536 + 318, 256, 0, stream>>>(Hh, W2T, eb2, gw2, perm, counts,
                                              gval, Yt, Hh, partial, ew1, ew2,
                                              W1T, W2T, (const char*)s4,
                                              (const char*)s8, (const char*)s16,
                                              bb, 1536, 318);
    // untranspose+residual + Hh/W2T/aux/partial restores
    k_untr<<<6144 + 73, 256, 0, stream>>>(Yt, s32, out32, (const char*)s4,
                                          (const char*)s8, (const char*)s16, bb, 73);
    // restore Yt region with real s4 data
    hipMemcpyAsync(bb, s4, (size_t)TAILBYTES, hipMemcpyDeviceToDevice, stream);
}

// Round 9
// 454.619 us; speedup vs baseline: 1.6717x; 1.6717x over previous
//
#include <hip/hip_runtime.h>
#include <cstddef>

#define CCH 768
#define CHUNK 262144u

// ---- d_out scratch carve (256 KiB chunks) ----
// [0,48)    Yt (bf16)     -> tail memcpy
// [48,96)   Hh (bf16)     -> restored in untr
// [96,114)  W2T           -> restored in untr
// [114,115) aux           -> restored in untr
// [115,121) partial       -> restored in untr
// [121,169) Xh            -> restored in exp2
// [169,178) GWh+GWl       -> restored in exp1
// [178,226) Xl            -> restored in exp1
// [226,244) W1T           -> restored in exp2
// early s4 [244,768) + s8 + s16: gate 500, exp1 280, exp2 250, untr 70
#define OFF_YT    0u
#define OFF_HH    12582912u
#define OFF_W2T   25165824u
#define OFF_AUX   29884416u
#define OFF_PART  30146560u
#define OFF_XH    31719424u
#define OFF_GWH   44302336u
#define OFF_GWL   45481984u
#define OFF_XL    46661632u
#define OFF_W1T   59244544u
#define TAILBYTES 12582912u

typedef __attribute__((ext_vector_type(8))) short short8v;
typedef __attribute__((ext_vector_type(4))) float f32x4;

__device__ __forceinline__ void gl16(const void* g, void* l) {
    __builtin_amdgcn_global_load_lds(
        (const __attribute__((address_space(1))) void*)g,
        (__attribute__((address_space(3))) void*)l, 16, 0, 0);
}

__device__ __forceinline__ void copy_chunk(int g, const char* s4b, const char* s8b,
                                           const char* s16b, char* bb) {
    const char* src = (g < 768) ? s4b + (size_t)g * CHUNK
                    : (g < 1152) ? s8b + (size_t)(g - 768) * CHUNK
                                 : s16b + (size_t)(g - 1152) * CHUNK;
    const uint4* s = (const uint4*)src;
    uint4* d = (uint4*)(bb + (size_t)g * CHUNK);
    int t = threadIdx.x;
#pragma unroll 8
    for (int it = 0; it < 64; ++it) d[it * 256 + t] = s[it * 256 + t];
}

__device__ __forceinline__ float gelu_tanh(float x) {
    // JAX default gelu (approximate=True)
    float u = 0.7978845608028654f * (x + 0.044715f * x * x * x);
    float e = __expf(2.0f * u);
    float t = 1.0f - 2.0f / (e + 1.0f);
    return 0.5f * x * (1.0f + t);
}

__device__ __forceinline__ short f2b(float f) {
    unsigned u = __float_as_uint(f);
    unsigned r = (u + 0x7FFFu + ((u >> 16) & 1u)) >> 16;
    return (short)r;
}

__device__ __forceinline__ float b2f(short s) {
    return __uint_as_float(((unsigned)(unsigned short)s) << 16);
}

// z<8: BCHW->token-major bf16 hi/lo transpose of s32. z==8: gate W1 hi/lo
// transposed convert. Also zeroes counts/cursors.
__global__ __launch_bounds__(256) void k_prep(const float* __restrict__ s32,
                                              const float* __restrict__ gw1,
                                              short* __restrict__ Xh,
                                              short* __restrict__ Xl,
                                              short* __restrict__ GWh,
                                              short* __restrict__ GWl,
                                              int* __restrict__ az) {
    int z = blockIdx.z;
    int tx = threadIdx.x, ty = threadIdx.y;
    if (z == 0 && blockIdx.x == 0 && blockIdx.y == 0 && ty == 0 && tx < 16)
        az[tx] = 0;
    __shared__ float tile[32][33];
    if (z < 8) {
        int c0 = blockIdx.y * 32, hw0 = blockIdx.x * 32;
        const float* s = s32 + (size_t)z * CCH * 1024;
#pragma unroll
        for (int i = 0; i < 4; ++i)
            tile[ty + 8 * i][tx] = s[(size_t)(c0 + ty + 8 * i) * 1024 + hw0 + tx];
        __syncthreads();
#pragma unroll
        for (int i = 0; i < 4; ++i) {
            int r = ty + 8 * i;
            int n = z * 1024 + hw0 + r;
            float v = tile[tx][r];
            short h = f2b(v);
            Xh[(size_t)n * CCH + c0 + tx] = h;
            Xl[(size_t)n * CCH + c0 + tx] = f2b(v - b2f(h));
        }
    } else {
        if (blockIdx.x >= 24) return;
        int ci0 = blockIdx.x * 32, co0 = blockIdx.y * 32;
#pragma unroll
        for (int i = 0; i < 4; ++i)
            tile[ty + 8 * i][tx] = gw1[(size_t)(ci0 + ty + 8 * i) * CCH + co0 + tx];
        __syncthreads();
#pragma unroll
        for (int i = 0; i < 4; ++i) {
            int co = co0 + ty + 8 * i;
            float v = tile[tx][ty + 8 * i];
            short h = f2b(v);
            GWh[(size_t)co * CCH + ci0 + tx] = h;
            GWl[(size_t)co * CCH + ci0 + tx] = f2b(v - b2f(h));
        }
    }
}

// 128x128-tile bf16 MFMA GEMM, 4 waves (64x64 quadrants), 2-phase
// double-buffered global_load_lds pipeline. Appended copy/restore chunks per
// mode; MODE 0 additionally carries 4608 expert-weight convert blocks.
// MODE 0: split-bf16: partial logits = gelu((Xh+Xl)@(GWh+GWl)^T + gb1) @ W2
// MODE 1: Hh[ofs+p] = f2b(gelu(Xh[perm] @ W1T^T + eb1))
// MODE 2: Yt[perm[ofs+p]] = f2b((Hh @ W2T^T + eb2)*gval)  (bf16 token-major)
template <int MODE>
__global__ __launch_bounds__(256) void k_mfma(const short* __restrict__ Ahp,
                                              const short* __restrict__ Alp,
                                              const short* __restrict__ Bhp,
                                              const short* __restrict__ Blp,
                                              const float* __restrict__ bias,
                                              const float* __restrict__ gw2,
                                              const int* __restrict__ perm,
                                              const int* __restrict__ counts,
                                              const float* __restrict__ gval,
                                              short* __restrict__ Yt,
                                              short* __restrict__ Hout,
                                              float* __restrict__ partial,
                                              const float* __restrict__ ew1,
                                              const float* __restrict__ ew2,
                                              short* __restrict__ W1T,
                                              short* __restrict__ W2T,
                                              const char* __restrict__ s4b,
                                              const char* __restrict__ s8b,
                                              const char* __restrict__ s16b,
                                              char* __restrict__ bb,
                                              int ngemm, int ncopy) {
    __shared__ __align__(16) short lds[32768];
    int bid = blockIdx.x;
    int t = threadIdx.x;
    if (bid >= ngemm) {
        int i = bid - ngemm;
        if (i < ncopy) {
            int g;
            if (MODE == 0) g = 244 + i;
            else if (MODE == 1) g = (i < 57) ? 169 + i : 744 + (i - 57);
            else g = (i < 48) ? 121 + i : (i < 66) ? 226 + (i - 48) : 1024 + (i - 66);
            copy_chunk(g, s4b, s8b, s16b, bb);
        } else if (MODE == 0) {
            int j = i - ncopy;  // 0..4607 expert-weight converts
            int mat = j / 576, q = j % 576;
            int ci0 = (q % 24) * 32, co0 = (q / 24) * 32;
            const float* src = (mat < 4 ? ew1 : ew2) + (size_t)(mat & 3) * CCH * CCH;
            short* dst = (mat < 4 ? W1T : W2T) + (size_t)(mat & 3) * CCH * CCH;
            float* tile = (float*)lds;  // [32][33]
            int tx = t & 31, ty = t >> 5;
#pragma unroll
            for (int i4 = 0; i4 < 4; ++i4)
                tile[(ty + 8 * i4) * 33 + tx] =
                    src[(size_t)(ci0 + ty + 8 * i4) * CCH + co0 + tx];
            __syncthreads();
#pragma unroll
            for (int i4 = 0; i4 < 4; ++i4) {
                int co = co0 + ty + 8 * i4;
                dst[(size_t)co * CCH + ci0 + tx] = f2b(tile[tx * 33 + ty + 8 * i4]);
            }
        }
        return;
    }

    int cbk = bid % 6;
    int mt = bid / 6;
    int c0 = cbk * 128;
    int e = 0, ts = mt, cnt = 1 << 30, ofs = 0, mrow0 = 0;
    if (MODE == 0) {
        mrow0 = mt * 128;
    } else {
        e = mt >> 6;
        ts = mt & 63;
        int n0 = counts[0], n1 = counts[1], n2 = counts[2], n3 = counts[3];
        cnt = (e == 0) ? n0 : (e == 1) ? n1 : (e == 2) ? n2 : n3;
        if (ts * 128 >= cnt) return;
        ofs = (e > 0 ? n0 : 0) + (e > 1 ? n1 : 0) + (e > 2 ? n2 : 0);
    }

    int lane = t & 63, w = t >> 6;
    int wr = w >> 1, wc = w & 1;
    int lrow = lane & 15, lk8 = lane >> 4;

    const short* aS[4];
    const short* bS[4];
    const short* alS[2];
    const short* blS[2];
    int dA[4];

    if (MODE == 0) {
#pragma unroll
        for (int i = 0; i < 2; ++i) {
            int c = 2 * w + i;
            int row = c * 16 + lrow;
            int koff = lk8 * 8;
            aS[i]  = Ahp + (size_t)(mrow0 + row) * CCH + koff;
            alS[i] = Alp + (size_t)(mrow0 + row) * CCH + koff;
            bS[i]  = Bhp + (size_t)(c0 + row) * CCH + koff;
            blS[i] = Blp + (size_t)(c0 + row) * CCH + koff;
            dA[i] = c * 512;
        }
    } else {
        size_t eoff = (size_t)e * CCH * CCH;
#pragma unroll
        for (int i = 0; i < 4; ++i) {
            int c = 4 * w + i;
            int g = c >> 1, ph = c & 1;
            int row = g * 16 + lrow;
            int koff = ph * 32 + lk8 * 8;
            int pl = ts * 128 + row;
            int pc = pl < cnt ? pl : cnt - 1;
            int arow = (MODE == 1) ? perm[ofs + pc] : (ofs + pc);
            aS[i] = Ahp + (size_t)arow * CCH + koff;
            bS[i] = Bhp + eoff + (size_t)(c0 + row) * CCH + koff;
            dA[i] = c * 512;
        }
    }

    f32x4 acc[4][4] = {};

    if (MODE == 0) {
        auto stage = [&](int b, int k0) {
            short* L = lds + b * 16384;
#pragma unroll
            for (int i = 0; i < 2; ++i) {
                gl16(aS[i] + k0, L + dA[i]);
                gl16(bS[i] + k0, L + 4096 + dA[i]);
                gl16(alS[i] + k0, L + 8192 + dA[i]);
                gl16(blS[i] + k0, L + 12288 + dA[i]);
            }
        };
        stage(0, 0);
        __syncthreads();
        for (int tt = 0; tt < 24; ++tt) {
            int cur = tt & 1;
            if (tt < 23) stage(cur ^ 1, (tt + 1) * 32);
            const short* L = lds + cur * 16384;
            short8v af[4], bf[4], xf[4];
#pragma unroll
            for (int m = 0; m < 4; ++m)
                af[m] = *(const short8v*)(L + ((wr * 4 + m) * 64 + lane) * 8);
#pragma unroll
            for (int n = 0; n < 4; ++n)
                bf[n] = *(const short8v*)(L + 4096 + ((wc * 4 + n) * 64 + lane) * 8);
#pragma unroll
            for (int m = 0; m < 4; ++m)
#pragma unroll
                for (int n = 0; n < 4; ++n)
                    acc[m][n] = __builtin_amdgcn_mfma_f32_16x16x32_bf16(af[m], bf[n], acc[m][n], 0, 0, 0);
#pragma unroll
            for (int n = 0; n < 4; ++n)
                xf[n] = *(const short8v*)(L + 12288 + ((wc * 4 + n) * 64 + lane) * 8);
#pragma unroll
            for (int m = 0; m < 4; ++m)
#pragma unroll
                for (int n = 0; n < 4; ++n)
                    acc[m][n] = __builtin_amdgcn_mfma_f32_16x16x32_bf16(af[m], xf[n], acc[m][n], 0, 0, 0);
#pragma unroll
            for (int m = 0; m < 4; ++m)
                xf[m] = *(const short8v*)(L + 8192 + ((wr * 4 + m) * 64 + lane) * 8);
#pragma unroll
            for (int m = 0; m < 4; ++m)
#pragma unroll
                for (int n = 0; n < 4; ++n)
                    acc[m][n] = __builtin_amdgcn_mfma_f32_16x16x32_bf16(xf[m], bf[n], acc[m][n], 0, 0, 0);
            __syncthreads();
        }
    } else {
        auto stage = [&](int b, int k0) {
            short* L = lds + b * 16384;
#pragma unroll
            for (int i = 0; i < 4; ++i) {
                gl16(aS[i] + k0, L + dA[i]);
                gl16(bS[i] + k0, L + 8192 + dA[i]);
            }
        };
        stage(0, 0);
        __syncthreads();
        for (int tt = 0; tt < 12; ++tt) {
            int cur = tt & 1;
            if (tt < 11) stage(cur ^ 1, (tt + 1) * 64);
            const short* L = lds + cur * 16384;
#pragma unroll
            for (int kk = 0; kk < 2; ++kk) {
                short8v af[4], bf[4];
#pragma unroll
                for (int m = 0; m < 4; ++m)
                    af[m] = *(const short8v*)(L + (((wr * 4 + m) * 2 + kk) * 64 + lane) * 8);
#pragma unroll
                for (int n = 0; n < 4; ++n)
                    bf[n] = *(const short8v*)(L + 8192 + (((wc * 4 + n) * 2 + kk) * 64 + lane) * 8);
#pragma unroll
                for (int m = 0; m < 4; ++m)
#pragma unroll
                    for (int n = 0; n < 4; ++n)
                        acc[m][n] = __builtin_amdgcn_mfma_f32_16x16x32_bf16(af[m], bf[n], acc[m][n], 0, 0, 0);
            }
            __syncthreads();
        }
    }

    int cl = lane & 15, rh = (lane >> 4) * 4;
    if (MODE == 0) {
        int cb2 = cbk * 2 + wc;
        float bv[4];
        float4 w2v[4];
#pragma unroll
        for (int n_ = 0; n_ < 4; ++n_) {
            int col = c0 + wc * 64 + n_ * 16 + cl;
            bv[n_] = bias[col];
            w2v[n_] = *(const float4*)(gw2 + col * 4);
        }
#pragma unroll
        for (int m = 0; m < 4; ++m) {
#pragma unroll
            for (int ri = 0; ri < 4; ++ri) {
                float s0 = 0.f, s1 = 0.f, s2 = 0.f, s3 = 0.f;
#pragma unroll
                for (int n_ = 0; n_ < 4; ++n_) {
                    float g = gelu_tanh(acc[m][n_][ri] + bv[n_]);
                    s0 = fmaf(g, w2v[n_].x, s0);
                    s1 = fmaf(g, w2v[n_].y, s1);
                    s2 = fmaf(g, w2v[n_].z, s2);
                    s3 = fmaf(g, w2v[n_].w, s3);
                }
#pragma unroll
                for (int off = 1; off < 16; off <<= 1) {
                    s0 += __shfl_xor(s0, off);
                    s1 += __shfl_xor(s1, off);
                    s2 += __shfl_xor(s2, off);
                    s3 += __shfl_xor(s3, off);
                }
                if (cl == 0) {
                    int row = mrow0 + wr * 64 + m * 16 + rh + ri;
                    float4 pv;
                    pv.x = s0; pv.y = s1; pv.z = s2; pv.w = s3;
                    *(float4*)(partial + (size_t)(cb2 * 8192 + row) * 4) = pv;
                }
            }
        }
    } else {
#pragma unroll
        for (int n = 0; n < 4; ++n) {
            int col = c0 + wc * 64 + n * 16 + cl;
            float bv = bias[e * CCH + col];
#pragma unroll
            for (int m = 0; m < 4; ++m) {
#pragma unroll
                for (int ri = 0; ri < 4; ++ri) {
                    int p = ts * 128 + wr * 64 + m * 16 + rh + ri;
                    if (p < cnt) {
                        float v = acc[m][n][ri] + bv;
                        if (MODE == 1) {
                            Hout[(size_t)(ofs + p) * CCH + col] = f2b(gelu_tanh(v));
                        } else {
                            int nn = perm[ofs + p];
                            Yt[(size_t)nn * CCH + col] = f2b(v * gval[nn]);
                        }
                    }
                }
            }
        }
    }
}

// sum 12 partial-logit slabs + b2 -> argmax / softmax top-1 / counts
__global__ __launch_bounds__(256) void k_route(const float* __restrict__ partial,
                                               const float* __restrict__ b2,
                                               int* __restrict__ idx,
                                               float* __restrict__ gval,
                                               int* __restrict__ counts) {
    int n = blockIdx.x * 256 + threadIdx.x;
    float l0 = b2[0], l1 = b2[1], l2 = b2[2], l3 = b2[3];
#pragma unroll
    for (int p = 0; p < 12; ++p) {
        float4 v = *(const float4*)(partial + ((size_t)p * 8192 + n) * 4);
        l0 += v.x; l1 += v.y; l2 += v.z; l3 += v.w;
    }
    int e = 0;
    float m = l0;
    if (l1 > m) { m = l1; e = 1; }
    if (l2 > m) { m = l2; e = 2; }
    if (l3 > m) { m = l3; e = 3; }
    float s = __expf(l0 - m) + __expf(l1 - m) + __expf(l2 - m) + __expf(l3 - m);
    idx[n] = e;
    gval[n] = 1.0f / s;
    atomicAdd(counts + e, 1);
}

// scatter with in-register prefix over the finalized counts
__global__ __launch_bounds__(256) void k_scatter(const int* __restrict__ idx,
                                                 const int* __restrict__ counts,
                                                 int* __restrict__ cursors,
                                                 int* __restrict__ perm) {
    int n = blockIdx.x * 256 + threadIdx.x;
    int e = idx[n];
    int run = 0;
#pragma unroll
    for (int ee = 0; ee < 4; ++ee) {
        int c = counts[ee];
        if (e == ee) {
            int pos = run + atomicAdd(cursors + ee, 1);
            perm[pos] = n;
        }
        run += c;
    }
}

// out32 = Yt(bf16 token-major) + s32 (coalesced); plus restore-copy chunks
__global__ __launch_bounds__(256) void k_untr(const short* __restrict__ Yt,
                                              const float* __restrict__ s32,
                                              float* __restrict__ out32,
                                              const char* __restrict__ s4b,
                                              const char* __restrict__ s8b,
                                              const char* __restrict__ s16b,
                                              char* __restrict__ bb,
                                              int ncopy) {
    int bid = blockIdx.x;
    if (bid >= 6144) {
        int i = bid - 6144;
        if (i < ncopy) {
            int g = (i < 73) ? 48 + i : 1274 + (i - 73);
            copy_chunk(g, s4b, s8b, s16b, bb);
        }
        return;
    }
    __shared__ float tile[32][33];
    int hw0 = (bid & 31) * 32;
    int c0 = ((bid >> 5) % 24) * 32;
    int b = bid / 768;
    int t = threadIdx.x;
    int tx = t & 31, ty = t >> 5;
#pragma unroll
    for (int i = 0; i < 4; ++i) {
        int hwl = ty + 8 * i;
        tile[hwl][tx] = b2f(Yt[(size_t)(b * 1024 + hw0 + hwl) * CCH + c0 + tx]);
    }
    __syncthreads();
    const float* sp = s32 + (size_t)b * CCH * 1024;
    float* op = out32 + (size_t)b * CCH * 1024;
#pragma unroll
    for (int i = 0; i < 4; ++i) {
        size_t a = (size_t)(c0 + ty + 8 * i) * 1024 + hw0 + tx;
        op[a] = tile[tx][ty + 8 * i] + sp[a];
    }
}

extern "C" void kernel_launch(void* const* d_in, const int* in_sizes, int n_in,
                              void* d_out, int out_size, void* d_ws, size_t ws_size,
                              hipStream_t stream) {
    const float* s4  = (const float*)d_in[0];
    const float* s8  = (const float*)d_in[1];
    const float* s16 = (const float*)d_in[2];
    const float* s32 = (const float*)d_in[3];
    const float* gw1 = (const float*)d_in[4];
    const float* gb1 = (const float*)d_in[5];
    const float* gw2 = (const float*)d_in[6];
    const float* gb2 = (const float*)d_in[7];
    const float* ew1 = (const float*)d_in[8];
    const float* eb1 = (const float*)d_in[9];
    const float* ew2 = (const float*)d_in[10];
    const float* eb2 = (const float*)d_in[11];

    char* bb = (char*)d_out;
    short* Yt      = (short*)(bb + OFF_YT);
    short* Hh      = (short*)(bb + OFF_HH);
    short* W2T     = (short*)(bb + OFF_W2T);
    int*   iaux    = (int*)(bb + OFF_AUX);
    int*   idx     = iaux;            // 8192
    int*   perm    = iaux + 8192;     // 8192
    int*   counts  = iaux + 16384;    // 4
    int*   cursors = iaux + 16388;    // 4
    float* gval    = (float*)(iaux + 16400);  // 8192
    float* partial = (float*)(bb + OFF_PART);
    short* Xh      = (short*)(bb + OFF_XH);
    short* GWh     = (short*)(bb + OFF_GWH);
    short* GWl     = (short*)(bb + OFF_GWL);
    short* Xl      = (short*)(bb + OFF_XL);
    short* W1T     = (short*)(bb + OFF_W1T);
    float* out32   = (float*)(bb + (size_t)1344 * CHUNK);

    k_prep<<<dim3(32, 24, 9), dim3(32, 8), 0, stream>>>(s32, gw1, Xh, Xl, GWh, GWl,
                                                        iaux + 16384);
    // gate (split-bf16 GEMM + fused W2 partials) + 500 copies + 4608 ew converts
    k_mfma<0><<<384 + 500 + 4608, 256, 0, stream>>>(Xh, Xl, GWh, GWl, gb1, gw2,
                                                    perm, counts, gval, Yt, Hh,
                                                    partial, ew1, ew2, W1T, W2T,
                                                    (const char*)s4, (const char*)s8,
                                                    (const char*)s16, bb, 384, 500);
    k_route<<<32, 256, 0, stream>>>(partial, gb2, idx, gval, counts);
    k_scatter<<<32, 256, 0, stream>>>(idx, counts, cursors, perm);
    // expert layer 1 + GW/Xl restores (57) + 280 early copies
    k_mfma<1><<<1536 + 337, 256, 0, stream>>>(Xh, Xl, W1T, GWl, eb1, gw2,
                                              perm, counts, gval, Yt, Hh,
                                              partial, ew1, ew2, W1T, W2T,
                                              (const char*)s4, (const char*)s8,
                                              (const char*)s16, bb, 1536, 337);
    // expert layer 2 + Xh/W1T restores (66) + 250 early copies
    k_mfma<2><<<1536 + 316, 256, 0, stream>>>(Hh, Xl, W2T, GWl, eb2, gw2,
                                              perm, counts, gval, Yt, Hh,
                                              partial, ew1, ew2, W1T, W2T,
                                              (const char*)s4, (const char*)s8,
                                              (const char*)s16, bb, 1536, 316);
    // untranspose+residual + Hh/W2T/aux/partial restores (73) + 70 early copies
    k_untr<<<6144 + 143, 256, 0, stream>>>(Yt, s32, out32, (const char*)s4,
                                           (const char*)s8, (const char*)s16, bb, 143);
    // restore Yt region with real s4 data
    hipMemcpyAsync(bb, s4, (size_t)TAILBYTES, hipMemcpyDeviceToDevice, stream);
}

// Round 10
// 365.833 us; speedup vs baseline: 2.0774x; 1.2427x over previous
//
#include <hip/hip_runtime.h>
#include <cstddef>

#define CCH 768
#define CHUNK 262144u

// ---- d_out scratch carve (256 KiB chunks) — EXACT R6 layout ----
// tail [0,170): Yt(f32,96) Hh(48) W2T(18) aux+partial  -> final memcpy
// [170,227)  Xl, GWh, GWl (dead after gate)            -> restored in exp1
// [227,293)  Xh, W1T (dead after exp1)                 -> restored in exp2
// early s4 [293,768) + s8 [768,1152)                   -> restored in gate
// s16 [1152,1344): first 96 in exp1, last 96 in exp2
#define OFF_YT    0u
#define OFF_HH    25165824u
#define OFF_W2T   37748736u
#define OFF_AUX   42467328u
#define OFF_PART  42631424u
#define TAILBYTES 44564480u
#define OFF_XL    44564480u
#define OFF_GWH   57147392u
#define OFF_GWL   58327040u
#define OFF_XH    59506688u
#define OFF_W1T   72089600u

typedef __attribute__((ext_vector_type(8))) short short8v;
typedef __attribute__((ext_vector_type(4))) float f32x4;

__device__ __forceinline__ void gl16(const void* g, void* l) {
    __builtin_amdgcn_global_load_lds(
        (const __attribute__((address_space(1))) void*)g,
        (__attribute__((address_space(3))) void*)l, 16, 0, 0);
}

__device__ __forceinline__ void copy_chunk(int g, const char* s4b, const char* s8b,
                                           const char* s16b, char* bb) {
    const char* src = (g < 768) ? s4b + (size_t)g * CHUNK
                    : (g < 1152) ? s8b + (size_t)(g - 768) * CHUNK
                                 : s16b + (size_t)(g - 1152) * CHUNK;
    const uint4* s = (const uint4*)src;
    uint4* d = (uint4*)(bb + (size_t)g * CHUNK);
    int t = threadIdx.x;
#pragma unroll 8
    for (int it = 0; it < 64; ++it) d[it * 256 + t] = s[it * 256 + t];
}

__device__ __forceinline__ float gelu_tanh(float x) {
    // JAX default gelu (approximate=True)
    float u = 0.7978845608028654f * (x + 0.044715f * x * x * x);
    float e = __expf(2.0f * u);
    float t = 1.0f - 2.0f / (e + 1.0f);
    return 0.5f * x * (1.0f + t);
}

__device__ __forceinline__ short f2b(float f) {
    unsigned u = __float_as_uint(f);
    unsigned r = (u + 0x7FFFu + ((u >> 16) & 1u)) >> 16;
    return (short)r;
}

__device__ __forceinline__ float b2f(short s) {
    return __uint_as_float(((unsigned)(unsigned short)s) << 16);
}

// z<8: BCHW->token-major bf16 hi/lo transpose of s32. z==8: gate W1 hi/lo
// transposed convert. Also zeroes counts (which double as scatter cursors).
__global__ __launch_bounds__(256) void k_prep(const float* __restrict__ s32,
                                              const float* __restrict__ gw1,
                                              short* __restrict__ Xh,
                                              short* __restrict__ Xl,
                                              short* __restrict__ GWh,
                                              short* __restrict__ GWl,
                                              int* __restrict__ az) {
    int z = blockIdx.z;
    int tx = threadIdx.x, ty = threadIdx.y;
    if (z == 0 && blockIdx.x == 0 && blockIdx.y == 0 && ty == 0 && tx < 8)
        az[tx] = 0;
    __shared__ float tile[32][33];
    if (z < 8) {
        int c0 = blockIdx.y * 32, hw0 = blockIdx.x * 32;
        const float* s = s32 + (size_t)z * CCH * 1024;
#pragma unroll
        for (int i = 0; i < 4; ++i)
            tile[ty + 8 * i][tx] = s[(size_t)(c0 + ty + 8 * i) * 1024 + hw0 + tx];
        __syncthreads();
#pragma unroll
        for (int i = 0; i < 4; ++i) {
            int r = ty + 8 * i;
            int n = z * 1024 + hw0 + r;
            float v = tile[tx][r];
            short h = f2b(v);
            Xh[(size_t)n * CCH + c0 + tx] = h;
            Xl[(size_t)n * CCH + c0 + tx] = f2b(v - b2f(h));
        }
    } else {
        if (blockIdx.x >= 24) return;
        int ci0 = blockIdx.x * 32, co0 = blockIdx.y * 32;
#pragma unroll
        for (int i = 0; i < 4; ++i)
            tile[ty + 8 * i][tx] = gw1[(size_t)(ci0 + ty + 8 * i) * CCH + co0 + tx];
        __syncthreads();
#pragma unroll
        for (int i = 0; i < 4; ++i) {
            int co = co0 + ty + 8 * i;
            float v = tile[tx][ty + 8 * i];
            short h = f2b(v);
            GWh[(size_t)co * CCH + ci0 + tx] = h;
            GWl[(size_t)co * CCH + ci0 + tx] = f2b(v - b2f(h));
        }
    }
}

// 128x128-tile bf16 MFMA GEMM, 4 waves (64x64 quadrants), 2-phase
// double-buffered global_load_lds pipeline (R6-proven core). Appended copy
// chunks per mode; MODE 0 additionally carries 4608 expert-weight converts.
// MODE 0: split-bf16: partial logits = gelu((Xh+Xl)@(GWh+GWl)^T + gb1) @ W2
// MODE 1: Hh[ofs+p] = f2b(gelu(Xh[perm_e] @ W1T^T + eb1))
// MODE 2: Yt[perm_e[p]] = (Hh @ W2T^T + eb2)*gval   (f32 token-major)
template <int MODE>
__global__ __launch_bounds__(256) void k_mfma(const short* __restrict__ Ahp,
                                              const short* __restrict__ Alp,
                                              const short* __restrict__ Bhp,
                                              const short* __restrict__ Blp,
                                              const float* __restrict__ bias,
                                              const float* __restrict__ gw2,
                                              const int* __restrict__ perm,
                                              const int* __restrict__ counts,
                                              const float* __restrict__ gval,
                                              float* __restrict__ Yt,
                                              short* __restrict__ Hout,
                                              float* __restrict__ partial,
                                              const float* __restrict__ ew1,
                                              const float* __restrict__ ew2,
                                              short* __restrict__ W1T,
                                              short* __restrict__ W2T,
                                              const char* __restrict__ s4b,
                                              const char* __restrict__ s8b,
                                              const char* __restrict__ s16b,
                                              char* __restrict__ bb,
                                              int ngemm, int ncopy) {
    __shared__ __align__(16) short lds[32768];
    int bid = blockIdx.x;
    int t = threadIdx.x;
    if (bid >= ngemm) {
        int i = bid - ngemm;
        if (i < ncopy) {
            int g;
            if (MODE == 0) g = (i < 475) ? 293 + i : 768 + (i - 475);
            else if (MODE == 1) g = (i < 57) ? 170 + i : 1152 + (i - 57);
            else g = (i < 66) ? 227 + i : 1248 + (i - 66);
            copy_chunk(g, s4b, s8b, s16b, bb);
        } else if (MODE == 0) {
            int j = i - ncopy;  // 0..4607 expert-weight converts
            int mat = j / 576, q = j % 576;
            int ci0 = (q % 24) * 32, co0 = (q / 24) * 32;
            const float* src = (mat < 4 ? ew1 : ew2) + (size_t)(mat & 3) * CCH * CCH;
            short* dst = (mat < 4 ? W1T : W2T) + (size_t)(mat & 3) * CCH * CCH;
            float* tile = (float*)lds;  // [32][33]
            int tx = t & 31, ty = t >> 5;
#pragma unroll
            for (int i4 = 0; i4 < 4; ++i4)
                tile[(ty + 8 * i4) * 33 + tx] =
                    src[(size_t)(ci0 + ty + 8 * i4) * CCH + co0 + tx];
            __syncthreads();
#pragma unroll
            for (int i4 = 0; i4 < 4; ++i4) {
                int co = co0 + ty + 8 * i4;
                dst[(size_t)co * CCH + ci0 + tx] = f2b(tile[tx * 33 + ty + 8 * i4]);
            }
        }
        return;
    }

    int cbk = bid % 6;
    int mt = bid / 6;
    int c0 = cbk * 128;
    int e = 0, ts = mt, cnt = 1 << 30, ofs = 0, mrow0 = 0;
    if (MODE == 0) {
        mrow0 = mt * 128;
    } else {
        e = mt >> 6;
        ts = mt & 63;
        int n0 = counts[0], n1 = counts[1], n2 = counts[2], n3 = counts[3];
        cnt = (e == 0) ? n0 : (e == 1) ? n1 : (e == 2) ? n2 : n3;
        if (ts * 128 >= cnt) return;
        ofs = (e > 0 ? n0 : 0) + (e > 1 ? n1 : 0) + (e > 2 ? n2 : 0);
    }

    int lane = t & 63, w = t >> 6;
    int wr = w >> 1, wc = w & 1;
    int lrow = lane & 15, lk8 = lane >> 4;

    const short* aS[4];
    const short* bS[4];
    const short* alS[2];
    const short* blS[2];
    int dA[4];

    if (MODE == 0) {
#pragma unroll
        for (int i = 0; i < 2; ++i) {
            int c = 2 * w + i;
            int row = c * 16 + lrow;
            int koff = lk8 * 8;
            aS[i]  = Ahp + (size_t)(mrow0 + row) * CCH + koff;
            alS[i] = Alp + (size_t)(mrow0 + row) * CCH + koff;
            bS[i]  = Bhp + (size_t)(c0 + row) * CCH + koff;
            blS[i] = Blp + (size_t)(c0 + row) * CCH + koff;
            dA[i] = c * 512;
        }
    } else {
        size_t eoff = (size_t)e * CCH * CCH;
#pragma unroll
        for (int i = 0; i < 4; ++i) {
            int c = 4 * w + i;
            int g = c >> 1, ph = c & 1;
            int row = g * 16 + lrow;
            int koff = ph * 32 + lk8 * 8;
            int pl = ts * 128 + row;
            int pc = pl < cnt ? pl : cnt - 1;
            int arow = (MODE == 1) ? perm[e * 8192 + pc] : (ofs + pc);
            aS[i] = Ahp + (size_t)arow * CCH + koff;
            bS[i] = Bhp + eoff + (size_t)(c0 + row) * CCH + koff;
            dA[i] = c * 512;
        }
    }

    f32x4 acc[4][4] = {};

    if (MODE == 0) {
        auto stage = [&](int b, int k0) {
            short* L = lds + b * 16384;
#pragma unroll
            for (int i = 0; i < 2; ++i) {
                gl16(aS[i] + k0, L + dA[i]);
                gl16(bS[i] + k0, L + 4096 + dA[i]);
                gl16(alS[i] + k0, L + 8192 + dA[i]);
                gl16(blS[i] + k0, L + 12288 + dA[i]);
            }
        };
        stage(0, 0);
        __syncthreads();
        for (int tt = 0; tt < 24; ++tt) {
            int cur = tt & 1;
            if (tt < 23) stage(cur ^ 1, (tt + 1) * 32);
            const short* L = lds + cur * 16384;
            short8v af[4], bf[4], xf[4];
#pragma unroll
            for (int m = 0; m < 4; ++m)
                af[m] = *(const short8v*)(L + ((wr * 4 + m) * 64 + lane) * 8);
#pragma unroll
            for (int n = 0; n < 4; ++n)
                bf[n] = *(const short8v*)(L + 4096 + ((wc * 4 + n) * 64 + lane) * 8);
#pragma unroll
            for (int m = 0; m < 4; ++m)
#pragma unroll
                for (int n = 0; n < 4; ++n)
                    acc[m][n] = __builtin_amdgcn_mfma_f32_16x16x32_bf16(af[m], bf[n], acc[m][n], 0, 0, 0);
#pragma unroll
            for (int n = 0; n < 4; ++n)
                xf[n] = *(const short8v*)(L + 12288 + ((wc * 4 + n) * 64 + lane) * 8);
#pragma unroll
            for (int m = 0; m < 4; ++m)
#pragma unroll
                for (int n = 0; n < 4; ++n)
                    acc[m][n] = __builtin_amdgcn_mfma_f32_16x16x32_bf16(af[m], xf[n], acc[m][n], 0, 0, 0);
#pragma unroll
            for (int m = 0; m < 4; ++m)
                xf[m] = *(const short8v*)(L + 8192 + ((wr * 4 + m) * 64 + lane) * 8);
#pragma unroll
            for (int m = 0; m < 4; ++m)
#pragma unroll
                for (int n = 0; n < 4; ++n)
                    acc[m][n] = __builtin_amdgcn_mfma_f32_16x16x32_bf16(xf[m], bf[n], acc[m][n], 0, 0, 0);
            __syncthreads();
        }
    } else {
        auto stage = [&](int b, int k0) {
            short* L = lds + b * 16384;
#pragma unroll
            for (int i = 0; i < 4; ++i) {
                gl16(aS[i] + k0, L + dA[i]);
                gl16(bS[i] + k0, L + 8192 + dA[i]);
            }
        };
        stage(0, 0);
        __syncthreads();
        for (int tt = 0; tt < 12; ++tt) {
            int cur = tt & 1;
            if (tt < 11) stage(cur ^ 1, (tt + 1) * 64);
            const short* L = lds + cur * 16384;
#pragma unroll
            for (int kk = 0; kk < 2; ++kk) {
                short8v af[4], bf[4];
#pragma unroll
                for (int m = 0; m < 4; ++m)
                    af[m] = *(const short8v*)(L + (((wr * 4 + m) * 2 + kk) * 64 + lane) * 8);
#pragma unroll
                for (int n = 0; n < 4; ++n)
                    bf[n] = *(const short8v*)(L + 8192 + (((wc * 4 + n) * 2 + kk) * 64 + lane) * 8);
#pragma unroll
                for (int m = 0; m < 4; ++m)
#pragma unroll
                    for (int n = 0; n < 4; ++n)
                        acc[m][n] = __builtin_amdgcn_mfma_f32_16x16x32_bf16(af[m], bf[n], acc[m][n], 0, 0, 0);
            }
            __syncthreads();
        }
    }

    int cl = lane & 15, rh = (lane >> 4) * 4;
    if (MODE == 0) {
        int cb2 = cbk * 2 + wc;
        float bv[4];
        float4 w2v[4];
#pragma unroll
        for (int n_ = 0; n_ < 4; ++n_) {
            int col = c0 + wc * 64 + n_ * 16 + cl;
            bv[n_] = bias[col];
            w2v[n_] = *(const float4*)(gw2 + col * 4);
        }
#pragma unroll
        for (int m = 0; m < 4; ++m) {
#pragma unroll
            for (int ri = 0; ri < 4; ++ri) {
                float s0 = 0.f, s1 = 0.f, s2 = 0.f, s3 = 0.f;
#pragma unroll
                for (int n_ = 0; n_ < 4; ++n_) {
                    float g = gelu_tanh(acc[m][n_][ri] + bv[n_]);
                    s0 = fmaf(g, w2v[n_].x, s0);
                    s1 = fmaf(g, w2v[n_].y, s1);
                    s2 = fmaf(g, w2v[n_].z, s2);
                    s3 = fmaf(g, w2v[n_].w, s3);
                }
#pragma unroll
                for (int off = 1; off < 16; off <<= 1) {
                    s0 += __shfl_xor(s0, off);
                    s1 += __shfl_xor(s1, off);
                    s2 += __shfl_xor(s2, off);
                    s3 += __shfl_xor(s3, off);
                }
                if (cl == 0) {
                    int row = mrow0 + wr * 64 + m * 16 + rh + ri;
                    float4 pv;
                    pv.x = s0; pv.y = s1; pv.z = s2; pv.w = s3;
                    *(float4*)(partial + (size_t)(cb2 * 8192 + row) * 4) = pv;
                }
            }
        }
    } else {
#pragma unroll
        for (int n = 0; n < 4; ++n) {
            int col = c0 + wc * 64 + n * 16 + cl;
            float bv = bias[e * CCH + col];
#pragma unroll
            for (int m = 0; m < 4; ++m) {
#pragma unroll
                for (int ri = 0; ri < 4; ++ri) {
                    int p = ts * 128 + wr * 64 + m * 16 + rh + ri;
                    if (p < cnt) {
                        float v = acc[m][n][ri] + bv;
                        if (MODE == 1) {
                            Hout[(size_t)(ofs + p) * CCH + col] = f2b(gelu_tanh(v));
                        } else {
                            int nn = perm[e * 8192 + p];
                            Yt[(size_t)nn * CCH + col] = v * gval[nn];
                        }
                    }
                }
            }
        }
    }
}

// sum 12 partial-logit slabs + b2 -> top-1 softmax gate; scatter directly into
// per-expert perm regions (counts double as cursors — no separate scatter pass)
__global__ __launch_bounds__(256) void k_route(const float* __restrict__ partial,
                                               const float* __restrict__ b2,
                                               int* __restrict__ perm,
                                               float* __restrict__ gval,
                                               int* __restrict__ counts) {
    int n = blockIdx.x * 256 + threadIdx.x;
    float l0 = b2[0], l1 = b2[1], l2 = b2[2], l3 = b2[3];
#pragma unroll
    for (int p = 0; p < 12; ++p) {
        float4 v = *(const float4*)(partial + ((size_t)p * 8192 + n) * 4);
        l0 += v.x; l1 += v.y; l2 += v.z; l3 += v.w;
    }
    int e = 0;
    float m = l0;
    if (l1 > m) { m = l1; e = 1; }
    if (l2 > m) { m = l2; e = 2; }
    if (l3 > m) { m = l3; e = 3; }
    float s = __expf(l0 - m) + __expf(l1 - m) + __expf(l2 - m) + __expf(l3 - m);
    gval[n] = 1.0f / s;
    int pos = atomicAdd(counts + e, 1);
    perm[e * 8192 + pos] = n;
}

// out32 = Yt (f32 token-major) + s32, both sides coalesced (exact R6 version)
__global__ __launch_bounds__(256) void k_untr(const float* __restrict__ Yt,
                                              const float* __restrict__ s32,
                                              float* __restrict__ out32) {
    __shared__ float tile[32][33];
    int b = blockIdx.z;
    int c0 = blockIdx.y * 32, hw0 = blockIdx.x * 32;
    int tx = threadIdx.x, ty = threadIdx.y;
#pragma unroll
    for (int i = 0; i < 4; ++i) {
        int hwl = ty + 8 * i;
        tile[hwl][tx] = Yt[(size_t)(b * 1024 + hw0 + hwl) * CCH + c0 + tx];
    }
    __syncthreads();
    const float* sp = s32 + (size_t)b * CCH * 1024;
    float* op = out32 + (size_t)b * CCH * 1024;
#pragma unroll
    for (int i = 0; i < 4; ++i) {
        size_t a = (size_t)(c0 + ty + 8 * i) * 1024 + hw0 + tx;
        op[a] = tile[tx][ty + 8 * i] + sp[a];
    }
}

extern "C" void kernel_launch(void* const* d_in, const int* in_sizes, int n_in,
                              void* d_out, int out_size, void* d_ws, size_t ws_size,
                              hipStream_t stream) {
    const float* s4  = (const float*)d_in[0];
    const float* s8  = (const float*)d_in[1];
    const float* s16 = (const float*)d_in[2];
    const float* s32 = (const float*)d_in[3];
    const float* gw1 = (const float*)d_in[4];
    const float* gb1 = (const float*)d_in[5];
    const float* gw2 = (const float*)d_in[6];
    const float* gb2 = (const float*)d_in[7];
    const float* ew1 = (const float*)d_in[8];
    const float* eb1 = (const float*)d_in[9];
    const float* ew2 = (const float*)d_in[10];
    const float* eb2 = (const float*)d_in[11];

    char* bb = (char*)d_out;
    float* Yt      = (float*)(bb + OFF_YT);
    short* Hh      = (short*)(bb + OFF_HH);
    short* W2T     = (short*)(bb + OFF_W2T);
    int*   iaux    = (int*)(bb + OFF_AUX);
    int*   perm    = iaux;              // 4 x 8192 (per-expert regions)
    int*   counts  = iaux + 32768;      // 4 (double as scatter cursors)
    float* gval    = (float*)(iaux + 32776);  // 8192
    float* partial = (float*)(bb + OFF_PART);
    short* Xl      = (short*)(bb + OFF_XL);
    short* GWh     = (short*)(bb + OFF_GWH);
    short* GWl     = (short*)(bb + OFF_GWL);
    short* Xh      = (short*)(bb + OFF_XH);
    short* W1T     = (short*)(bb + OFF_W1T);
    float* out32   = (float*)(bb + (size_t)1344 * CHUNK);

    k_prep<<<dim3(32, 24, 9), dim3(32, 8), 0, stream>>>(s32, gw1, Xh, Xl, GWh, GWl,
                                                        counts);
    // gate (split-bf16 GEMM + fused W2 partials) + 859 copies + 4608 ew converts
    k_mfma<0><<<384 + 859 + 4608, 256, 0, stream>>>(Xh, Xl, GWh, GWl, gb1, gw2,
                                                    perm, counts, gval, Yt, Hh,
                                                    partial, ew1, ew2, W1T, W2T,
                                                    (const char*)s4, (const char*)s8,
                                                    (const char*)s16, bb, 384, 859);
    k_route<<<32, 256, 0, stream>>>(partial, gb2, perm, gval, counts);
    // expert layer 1 + Xl/GW restores (57) + s16 first-half (96)
    k_mfma<1><<<1536 + 153, 256, 0, stream>>>(Xh, Xl, W1T, GWl, eb1, gw2,
                                              perm, counts, gval, Yt, Hh,
                                              partial, ew1, ew2, W1T, W2T,
                                              (const char*)s4, (const char*)s8,
                                              (const char*)s16, bb, 1536, 153);
    // expert layer 2 + Xh/W1T restores (66) + s16 second-half (96)
    k_mfma<2><<<1536 + 162, 256, 0, stream>>>(Hh, Xl, W2T, GWl, eb2, gw2,
                                              perm, counts, gval, Yt, Hh,
                                              partial, ew1, ew2, W1T, W2T,
                                              (const char*)s4, (const char*)s8,
                                              (const char*)s16, bb, 1536, 162);
    k_untr<<<dim3(32, 24, 8), dim3(32, 8), 0, stream>>>(Yt, s32, out32);
    // restore tail region [0,170) with real s4 data
    hipMemcpyAsync(bb, s4, (size_t)TAILBYTES, hipMemcpyDeviceToDevice, stream);
}